// Round 6
// baseline (60.052 us; speedup 1.0000x reference)
//
#include <hip/hip_runtime.h>

#define NB 8
#define TE 256
#define TD 256
#define ED 512
#define DU 256

// EpeT2 layout: [b][uq=u/4][t][ui=u%4]  (64 x 256 x 4 floats per b = 65536)
// -> score reads one float4 (u-quad) per lane: 16B/lane, 1KB/wave.

// K1: proj+exp, 32x64 tiles, 512 threads (8 waves): K-split. Lower 256
// threads (h=0) accumulate K-half 0, upper (h=1) K-half 1; partials
// combined via LDS before epilogue. 2 blocks/CU x 8 waves = 4 waves/SIMD.
__global__ __launch_bounds__(512) void proj_exp_kernel(
    const float* __restrict__ enc, const float* __restrict__ dec,
    const float* __restrict__ W1, const float* __restrict__ b1,
    const float* __restrict__ W2, const float* __restrict__ b2,
    float* __restrict__ Epd, float* __restrict__ EpeT2)
{
  __shared__ __align__(16) float As[2][32][34];
  __shared__ __align__(16) float Bs[2][32][64];
  __shared__ __align__(16) float comb[8][256];
  const int blk = blockIdx.x;
  const bool is_pe = blk < 256;
  const int sub = blk & 255;
  const int K = is_pe ? ED : DU;
  const int NTh = K >> 6;  // K-tiles per half (pe: 8, pd: 4)
  const float* __restrict__ A = is_pe ? enc : dec;
  const float* __restrict__ W = is_pe ? W1 : W2;
  const float* __restrict__ bias = is_pe ? b1 : b2;
  const int mt = sub >> 2, nt = sub & 3;
  const int m0 = mt * 32, n0 = nt * 64;
  const int tid = threadIdx.x;
  const int t = tid & 255;  // index within half
  const int h = tid >> 8;   // K-half
  const int k0base = h * (K >> 1);
  const int tx = t & 15, ty = t >> 4;
  const int at = t >> 3, ka = (t & 7) << 2;   // A: row, k-offset
  const int kb = t >> 4, jb = (t & 15) << 2;  // W: k-row, col-offset

  const float* __restrict__ Ap = A + (size_t)(m0 + at) * K + k0base + ka;
  const float* __restrict__ Wp = W + (size_t)(k0base + kb) * DU + n0 + jb;

  float acc[2][4] = {};
  float4 aV, wV0, wV1;

  auto loadr = [&](int k0) {
    aV = *(const float4*)(Ap + k0);
    wV0 = *(const float4*)(Wp + (size_t)k0 * DU);
    wV1 = *(const float4*)(Wp + (size_t)(k0 + 16) * DU);
  };

  loadr(0);
  for (int kt = 0; kt < NTh; ++kt) {
    As[h][ka + 0][at] = aV.x;
    As[h][ka + 1][at] = aV.y;
    As[h][ka + 2][at] = aV.z;
    As[h][ka + 3][at] = aV.w;
    *(float4*)&Bs[h][kb][jb] = wV0;
    *(float4*)&Bs[h][kb + 16][jb] = wV1;
    __syncthreads();
    if (kt + 1 < NTh) loadr((kt + 1) << 5);
#pragma unroll
    for (int kk = 0; kk < 32; ++kk) {
      const float2 a2 = *(const float2*)&As[h][kk][ty * 2];
      const float4 w4 = *(const float4*)&Bs[h][kk][tx * 4];
      acc[0][0] = fmaf(a2.x, w4.x, acc[0][0]);
      acc[0][1] = fmaf(a2.x, w4.y, acc[0][1]);
      acc[0][2] = fmaf(a2.x, w4.z, acc[0][2]);
      acc[0][3] = fmaf(a2.x, w4.w, acc[0][3]);
      acc[1][0] = fmaf(a2.y, w4.x, acc[1][0]);
      acc[1][1] = fmaf(a2.y, w4.y, acc[1][1]);
      acc[1][2] = fmaf(a2.y, w4.z, acc[1][2]);
      acc[1][3] = fmaf(a2.y, w4.w, acc[1][3]);
    }
    __syncthreads();
  }

  // ---- combine K-halves ----
  if (h == 1) {
#pragma unroll
    for (int r = 0; r < 2; ++r)
#pragma unroll
      for (int j = 0; j < 4; ++j) comb[r * 4 + j][t] = acc[r][j];
  }
  __syncthreads();
  if (h == 0) {
#pragma unroll
    for (int r = 0; r < 2; ++r)
#pragma unroll
      for (int j = 0; j < 4; ++j) acc[r][j] += comb[r * 4 + j][t];

    const float4 bv4 = *(const float4*)(bias + n0 + tx * 4);
    const float bvv[4] = {bv4.x, bv4.y, bv4.z, bv4.w};
    if (is_pe) {
      // u-quad interleaved write: thread owns uq = n0/4+tx, t = t0+ty*2(+r)
      const int b = m0 >> 8, t0 = m0 & 255;
      const int uqg = (b << 6) + (n0 >> 2) + tx;
      const int tg = t0 + ty * 2;
      float* dst = EpeT2 + ((size_t)uqg << 10) + (tg << 2);
      float4 o0, o1;
      o0.x = __expf(2.0f * (acc[0][0] + bvv[0]));
      o0.y = __expf(2.0f * (acc[0][1] + bvv[1]));
      o0.z = __expf(2.0f * (acc[0][2] + bvv[2]));
      o0.w = __expf(2.0f * (acc[0][3] + bvv[3]));
      o1.x = __expf(2.0f * (acc[1][0] + bvv[0]));
      o1.y = __expf(2.0f * (acc[1][1] + bvv[1]));
      o1.z = __expf(2.0f * (acc[1][2] + bvv[2]));
      o1.w = __expf(2.0f * (acc[1][3] + bvv[3]));
      *(float4*)dst = o0;
      *(float4*)(dst + 4) = o1;
    } else {
#pragma unroll
      for (int r = 0; r < 2; ++r) {
        const int m = m0 + ty * 2 + r;  // global dec row (b*256+s)
        float4 o;
        o.x = __expf(2.0f * (acc[r][0] + bvv[0]));
        o.y = __expf(2.0f * (acc[r][1] + bvv[1]));
        o.z = __expf(2.0f * (acc[r][2] + bvv[2]));
        o.w = __expf(2.0f * (acc[r][3] + bvv[3]));
        *(float4*)(Epd + ((size_t)m << 8) + n0 + tx * 4) = o;
      }
    }
  }
}

// K23: fused score+softmax+context, 512 threads (8 waves), grid 512 =
// (b, s-quad); XCD swizzle keeps each batch's blocks on one XCD.
// Phase 1 (u-split over h): pairwise-fraction form halves the rcp count:
//   Vwx/A + Vwy/B = (Vwx*B + Vwy*A) / (A*B);  A,B = Epd*Epe+1 >= 1.
// Epd/Vw read DIRECTLY from global with wave-uniform addresses -> compiler
// scalarizes to s_load (frees VALU + LDS + one barrier).
// Softmax WITHOUT max-subtract: |v| <= 2*sum|Vw| ~ 26, exp range safe in
// fp32; mathematically identical to the max-subtracted softmax.
// Phase 2: column-split ctx; enc read exactly once per block.
__global__ __launch_bounds__(512) void score_ctx_kernel(
    const float* __restrict__ Epd, const float* __restrict__ EpeT2,
    const float* __restrict__ Vw, const float* __restrict__ enc,
    float* __restrict__ attn, float* __restrict__ ctx)
{
  __shared__ __align__(16) float comb[4][256];   // u-half partials (4KB)
  __shared__ __align__(16) float att[4][256];    // probs (4KB)
  __shared__ float reds[4][4];

  const int blk0 = blockIdx.x;
  const int blk = ((blk0 & 7) << 6) | (blk0 >> 3);  // T1 XCD swizzle
  const int b = blk >> 6;
  const int s0 = (blk & 63) << 2;
  const int tid = threadIdx.x;
  const int t = tid & 255;  // enc position
  const int h = tid >> 8;   // u-half (0/1)

  const float4* __restrict__ pd4 =
      (const float4*)(Epd + (((size_t)((b << 8) + s0)) << 8));
  const float4* __restrict__ vw4 = (const float4*)Vw;
  const float* __restrict__ ep =
      EpeT2 + ((size_t)b << 16) + ((size_t)h << 15) + (t << 2);
  const int qb = h << 5;

  float a0 = 0.f, a1 = 0.f, a2 = 0.f, a3 = 0.f;
  float4 g = *(const float4*)ep;
#pragma unroll 4
  for (int q = 0; q < 32; ++q) {
    float4 gn;
    if (q + 1 < 32) gn = *(const float4*)(ep + ((size_t)(q + 1) << 10));
    const int qq = qb + q;
    const float4 vw = vw4[qq];
    const float4 e0 = pd4[qq];
    const float4 e1 = pd4[64 + qq];
    const float4 e2 = pd4[128 + qq];
    const float4 e3 = pd4[192 + qq];
    // row 0
    {
      const float A = fmaf(e0.x, g.x, 1.0f), B = fmaf(e0.y, g.y, 1.0f);
      float n = vw.x * B;
      n = fmaf(vw.y, A, n);
      a0 = fmaf(n, __builtin_amdgcn_rcpf(A * B), a0);
      const float C = fmaf(e0.z, g.z, 1.0f), D = fmaf(e0.w, g.w, 1.0f);
      float n2 = vw.z * D;
      n2 = fmaf(vw.w, C, n2);
      a0 = fmaf(n2, __builtin_amdgcn_rcpf(C * D), a0);
    }
    // row 1
    {
      const float A = fmaf(e1.x, g.x, 1.0f), B = fmaf(e1.y, g.y, 1.0f);
      float n = vw.x * B;
      n = fmaf(vw.y, A, n);
      a1 = fmaf(n, __builtin_amdgcn_rcpf(A * B), a1);
      const float C = fmaf(e1.z, g.z, 1.0f), D = fmaf(e1.w, g.w, 1.0f);
      float n2 = vw.z * D;
      n2 = fmaf(vw.w, C, n2);
      a1 = fmaf(n2, __builtin_amdgcn_rcpf(C * D), a1);
    }
    // row 2
    {
      const float A = fmaf(e2.x, g.x, 1.0f), B = fmaf(e2.y, g.y, 1.0f);
      float n = vw.x * B;
      n = fmaf(vw.y, A, n);
      a2 = fmaf(n, __builtin_amdgcn_rcpf(A * B), a2);
      const float C = fmaf(e2.z, g.z, 1.0f), D = fmaf(e2.w, g.w, 1.0f);
      float n2 = vw.z * D;
      n2 = fmaf(vw.w, C, n2);
      a2 = fmaf(n2, __builtin_amdgcn_rcpf(C * D), a2);
    }
    // row 3
    {
      const float A = fmaf(e3.x, g.x, 1.0f), B = fmaf(e3.y, g.y, 1.0f);
      float n = vw.x * B;
      n = fmaf(vw.y, A, n);
      a3 = fmaf(n, __builtin_amdgcn_rcpf(A * B), a3);
      const float C = fmaf(e3.z, g.z, 1.0f), D = fmaf(e3.w, g.w, 1.0f);
      float n2 = vw.z * D;
      n2 = fmaf(vw.w, C, n2);
      a3 = fmaf(n2, __builtin_amdgcn_rcpf(C * D), a3);
    }
    g = gn;
  }

  if (h == 1) {
    comb[0][t] = a0;
    comb[1][t] = a1;
    comb[2][t] = a2;
    comb[3][t] = a3;
  }
  __syncthreads();

  // ---- combine + no-max softmax on lower 4 waves ----
  const int wid = tid >> 6, lane = tid & 63;
  float e[4];
  if (h == 0) {
#pragma unroll
    for (int r = 0; r < 4; ++r) {
      const float v =
          -2.f * ((r == 0 ? a0 : r == 1 ? a1 : r == 2 ? a2 : a3) + comb[r][t]);
      e[r] = __expf(v);
      float s = e[r];
#pragma unroll
      for (int off = 32; off; off >>= 1) s += __shfl_xor(s, off);
      if (lane == 0) reds[r][wid] = s;
    }
  }
  __syncthreads();
  if (h == 0) {
#pragma unroll
    for (int r = 0; r < 4; ++r) {
      const float s = (reds[r][0] + reds[r][1]) + (reds[r][2] + reds[r][3]);
      const float p = e[r] * __builtin_amdgcn_rcpf(s);
      attn[(((size_t)((b << 8) + s0 + r)) << 8) + t] = p;
      att[r][t] = p;
    }
  }
  __syncthreads();

  // ---- Phase 2: ctx col c = tid, 4 rows. enc read once per block. ----
  const int c = tid;
  const float* __restrict__ encb = enc + ((size_t)b << 17) + c;
  float acc0 = 0.f, acc1 = 0.f, acc2 = 0.f, acc3 = 0.f;
#pragma unroll 2
  for (int t0 = 0; t0 < 256; t0 += 4) {
    const float4 p0 = *(const float4*)&att[0][t0];
    const float4 p1 = *(const float4*)&att[1][t0];
    const float4 p2 = *(const float4*)&att[2][t0];
    const float4 p3 = *(const float4*)&att[3][t0];
    const float pv0[4] = {p0.x, p0.y, p0.z, p0.w};
    const float pv1[4] = {p1.x, p1.y, p1.z, p1.w};
    const float pv2[4] = {p2.x, p2.y, p2.z, p2.w};
    const float pv3[4] = {p3.x, p3.y, p3.z, p3.w};
#pragma unroll
    for (int i = 0; i < 4; ++i) {
      const float ev = encb[(size_t)(t0 + i) << 9];
      acc0 = fmaf(pv0[i], ev, acc0);
      acc1 = fmaf(pv1[i], ev, acc1);
      acc2 = fmaf(pv2[i], ev, acc2);
      acc3 = fmaf(pv3[i], ev, acc3);
    }
  }
  float* __restrict__ cb = ctx + (((size_t)((b << 8) + s0)) << 9) + c;
  cb[0 * ED] = acc0;
  cb[1 * ED] = acc1;
  cb[2 * ED] = acc2;
  cb[3 * ED] = acc3;
}

extern "C" void kernel_launch(void* const* d_in, const int* in_sizes, int n_in,
                              void* d_out, int out_size, void* d_ws, size_t ws_size,
                              hipStream_t stream) {
  const float* enc = (const float*)d_in[0];
  const float* dec = (const float*)d_in[1];
  const float* W1 = (const float*)d_in[2];
  const float* b1 = (const float*)d_in[3];
  const float* W2 = (const float*)d_in[4];
  const float* b2 = (const float*)d_in[5];
  const float* Vw = (const float*)d_in[6];
  // Vb cancels in softmax — unused.

  float* ctx = (float*)d_out;                          // (8,256,512)
  float* attn = (float*)d_out + (size_t)NB * TD * ED;  // (8,256,256)
  float* Epd = (float*)d_ws;                           // 512K floats
  float* EpeT2 = Epd + (size_t)NB * TD * DU;           // 512K floats

  proj_exp_kernel<<<dim3(512), dim3(512), 0, stream>>>(enc, dec, W1, b1, W2,
                                                       b2, Epd, EpeT2);
  score_ctx_kernel<<<dim3(512), dim3(512), 0, stream>>>(Epd, EpeT2, Vw, enc,
                                                        attn, ctx);
}